// Round 2
// baseline (350.576 us; speedup 1.0000x reference)
//
#include <hip/hip_runtime.h>
#include <hip/hip_bf16.h>

// B=16, N=2048, DIM=256. out[b,i,j] = <pn_i, pn_j>, pn = normalize(x@W^T + b).
// bf16 MFMA both matmuls (fp32 accumulate); threshold 2e-2 >> bf16 err ~2e-3 (verified r1).

typedef __bf16 bf16x8 __attribute__((ext_vector_type(8)));
typedef float  f32x4  __attribute__((ext_vector_type(4)));

__device__ __forceinline__ void gl_lds16(const void* g, void* l) {
  __builtin_amdgcn_global_load_lds((const __attribute__((address_space(1))) void*)g,
                                   (__attribute__((address_space(3))) void*)l, 16, 0, 0);
}

__device__ __forceinline__ bf16x8 pack8(f32x4 a, f32x4 b) {
  bf16x8 r;
  r[0] = (__bf16)a[0]; r[1] = (__bf16)a[1]; r[2] = (__bf16)a[2]; r[3] = (__bf16)a[3];
  r[4] = (__bf16)b[0]; r[5] = (__bf16)b[1]; r[6] = (__bf16)b[2]; r[7] = (__bf16)b[3];
  return r;
}

// ---------------- Kernel 1: p = x@W^T + b ; pn = p/||p|| -> bf16 ----------------
// (unchanged from r1 — passed, theoretically ~10 µs)
__global__ __launch_bounds__(512, 1) void proj_kernel(
    const float* __restrict__ x, const float* __restrict__ W,
    const float* __restrict__ bq, __bf16* __restrict__ pn) {
  __shared__ __attribute__((aligned(16))) char ldsW[131072];  // 256x256 bf16 swizzled
  const int t = threadIdx.x;
  const int lane = t & 63;
  const int w = t >> 6;

  #pragma unroll
  for (int it = 0; it < 16; ++it) {
    int base = (it * 512 + t) * 8;
    int row  = base >> 8;
    int colb = (base & 255) * 2;
    f32x4 v0 = *(const f32x4*)(W + base);
    f32x4 v1 = *(const f32x4*)(W + base + 4);
    *(bf16x8*)(ldsW + row * 512 + (colb ^ ((row & 7) << 4))) = pack8(v0, v1);
  }
  __syncthreads();

  const int r0 = blockIdx.x * 128 + w * 16;
  const int arow = r0 + (lane & 15);
  const float* xrow = x + (size_t)arow * 256 + (lane >> 4) * 8;
  bf16x8 afr[8];
  #pragma unroll
  for (int kk = 0; kk < 8; ++kk) {
    f32x4 v0 = *(const f32x4*)(xrow + kk * 32);
    f32x4 v1 = *(const f32x4*)(xrow + kk * 32 + 4);
    afr[kk] = pack8(v0, v1);
  }

  f32x4 acc[16];
  #pragma unroll
  for (int ct = 0; ct < 16; ++ct) acc[ct] = (f32x4){0.f, 0.f, 0.f, 0.f};
  const int kb0 = (lane >> 4) * 16;
  #pragma unroll
  for (int ct = 0; ct < 16; ++ct) {
    int brow = ct * 16 + (lane & 15);
    const char* wb = ldsW + brow * 512;
    int sw = (brow & 7) << 4;
    #pragma unroll
    for (int kk = 0; kk < 8; ++kk) {
      bf16x8 bf = *(const bf16x8*)(wb + ((kk * 64 + kb0) ^ sw));
      acc[ct] = __builtin_amdgcn_mfma_f32_16x16x32_bf16(afr[kk], bf, acc[ct], 0, 0, 0);
    }
  }

  float bc[16];
  #pragma unroll
  for (int ct = 0; ct < 16; ++ct) bc[ct] = bq[ct * 16 + (lane & 15)];
  #pragma unroll
  for (int ct = 0; ct < 16; ++ct) {
    #pragma unroll
    for (int r = 0; r < 4; ++r) acc[ct][r] += bc[ct];
  }
  #pragma unroll
  for (int r = 0; r < 4; ++r) {
    float s = 0.f;
    #pragma unroll
    for (int ct = 0; ct < 16; ++ct) s += acc[ct][r] * acc[ct][r];
    s += __shfl_xor(s, 1); s += __shfl_xor(s, 2);
    s += __shfl_xor(s, 4); s += __shfl_xor(s, 8);
    float rn = rsqrtf(s);
    int rowg = r0 + (lane >> 4) * 4 + r;
    __bf16* dst = pn + (size_t)rowg * 256 + (lane & 15);
    #pragma unroll
    for (int ct = 0; ct < 16; ++ct) dst[ct * 16] = (__bf16)(acc[ct][r] * rn);
  }
}

// ---------------- Kernel 2: attn[b] = pn[b] @ pn[b]^T ----------------
// v2: stripe pipeline. Block = 128 output rows x 1024 cols (16 j-iters of 64 cols).
// A-tile staged once -> A-frags live in registers (64 VGPR); B double-buffered
// 2x32KB in the SAME 64KB LDS (A-LDS aliased after frag hoist). Stores of tile j
// drain during compute of tile j+1 -> per-iter barrier wait == HBM write wait.
// LDS 64KB + VGPR<=128 -> 2 blocks/CU for cross-block overlap.
__global__ __launch_bounds__(512, 4) void gram_kernel(
    const __bf16* __restrict__ pn, float* __restrict__ out) {
  __shared__ __attribute__((aligned(16))) char lds[65536];
  const int t = threadIdx.x;
  const int lane = t & 63;
  const int w = t >> 6;
  const int wr = w >> 1;        // 0..3: 32-row group
  const int wc = w & 1;         // 0..1: 32-col group
  const int bid = blockIdx.x;
  const int batch = bid >> 5;           // 32 blocks per batch
  const int stripe = (bid >> 1) & 15;   // 16 row-stripes of 128
  const int jhalf = bid & 1;            // 2 col-halves of 1024
  const char* pb = (const char*)(pn + (size_t)batch * 2048 * 256);
  const int i0 = stripe * 128;
  const int kb0 = (lane >> 4) * 16;

  // ---- stage A (128 rows x 512B = 64KB): linear LDS dest + pre-swizzled source ----
  #pragma unroll
  for (int i = 0; i < 8; ++i) {
    int off = (i * 512 + t) * 16;           // this thread's byte offset
    int row = off >> 9;
    int kb  = off & 511;
    gl_lds16(pb + (size_t)(i0 + row) * 512 + (kb ^ ((row & 7) << 4)),
             lds + i * 8192 + w * 1024);    // wave-uniform base + lane*16
  }
  __syncthreads();

  // ---- hoist A fragments: rows wr*32 + fr*16 + (lane&15), all K=256 ----
  bf16x8 afr[2][8];
  #pragma unroll
  for (int fr = 0; fr < 2; ++fr) {
    int row = wr * 32 + fr * 16 + (lane & 15);
    const char* ab = lds + row * 512;
    int sw = (row & 7) << 4;
    #pragma unroll
    for (int kk = 0; kk < 8; ++kk)
      afr[fr][kk] = *(const bf16x8*)(ab + ((kk * 64 + kb0) ^ sw));
  }
  __syncthreads();   // all A-frag reads done before B0 staging overwrites LDS

  const int jbase = jhalf * 1024;
  float* ob = out + (size_t)batch * 2048 * 2048;
  const int ro0 = i0 + wr * 32 + (lane >> 4) * 4;

  // ---- prologue: stage B(0) into buf0 (rows = pn rows jbase..+64) ----
  #pragma unroll
  for (int i = 0; i < 4; ++i) {
    int off = (i * 512 + t) * 16;
    int row = off >> 9;
    int kb  = off & 511;
    gl_lds16(pb + (size_t)(jbase + row) * 512 + (kb ^ ((row & 7) << 4)),
             lds + i * 8192 + w * 1024);
  }
  __syncthreads();

  for (int jj = 0; jj < 16; ++jj) {
    const char* buf = lds + (jj & 1) * 32768;
    // stage B(jj+1) into the other buffer (overlaps with compute below)
    if (jj < 15) {
      char* nb = lds + ((jj + 1) & 1) * 32768;
      int j0 = jbase + (jj + 1) * 64;
      #pragma unroll
      for (int i = 0; i < 4; ++i) {
        int off = (i * 512 + t) * 16;
        int row = off >> 9;
        int kb  = off & 511;
        gl_lds16(pb + (size_t)(j0 + row) * 512 + (kb ^ ((row & 7) << 4)),
                 nb + i * 8192 + w * 1024);
      }
    }
    // compute 128x64 tile: wave (wr,wc) -> 32x32 = 2x2 MFMA frags x 8 k-steps
    f32x4 acc[2][2];
    #pragma unroll
    for (int m = 0; m < 2; ++m)
      #pragma unroll
      for (int n = 0; n < 2; ++n) acc[m][n] = (f32x4){0.f, 0.f, 0.f, 0.f};
    #pragma unroll
    for (int kk = 0; kk < 8; ++kk) {
      bf16x8 bfr[2];
      #pragma unroll
      for (int n = 0; n < 2; ++n) {
        int row = wc * 32 + n * 16 + (lane & 15);
        bfr[n] = *(const bf16x8*)(buf + row * 512 + ((kk * 64 + kb0) ^ ((row & 7) << 4)));
      }
      #pragma unroll
      for (int m = 0; m < 2; ++m)
        #pragma unroll
        for (int n = 0; n < 2; ++n)
          acc[m][n] = __builtin_amdgcn_mfma_f32_16x16x32_bf16(afr[m][kk], bfr[n], acc[m][n], 0, 0, 0);
    }
    __syncthreads();  // B(jj+1) staged; prior stores mostly drained (this wait == HBM BW)
    // store tile jj (nontemporal: keep streaming 268MB out of L2, pn stays resident)
    int co0 = jbase + jj * 64 + wc * 32 + (lane & 15);
    #pragma unroll
    for (int m = 0; m < 2; ++m)
      #pragma unroll
      for (int n = 0; n < 2; ++n)
        #pragma unroll
        for (int r = 0; r < 4; ++r)
          __builtin_nontemporal_store(acc[m][n][r],
              &ob[(size_t)(ro0 + m * 16 + r) * 2048 + (co0 + n * 16)]);
  }
}

extern "C" void kernel_launch(void* const* d_in, const int* in_sizes, int n_in,
                              void* d_out, int out_size, void* d_ws, size_t ws_size,
                              hipStream_t stream) {
  const float* x  = (const float*)d_in[0];   // [16,2048,256]
  const float* Wq = (const float*)d_in[1];   // [256,256]
  const float* bq = (const float*)d_in[2];   // [256]
  float* out = (float*)d_out;                // [16,2048,2048]
  __bf16* pn = (__bf16*)d_ws;                // 32768*256 bf16 = 16 MB scratch

  proj_kernel<<<dim3(256), dim3(512), 0, stream>>>(x, Wq, bq, pn);
  gram_kernel<<<dim3(512), dim3(512), 0, stream>>>(pn, out);
}

// Round 3
// 322.941 us; speedup vs baseline: 1.0856x; 1.0856x over previous
//
#include <hip/hip_runtime.h>
#include <hip/hip_bf16.h>

// B=16, N=2048, DIM=256. out[b,i,j] = <pn_i, pn_j>, pn = normalize(x@W^T + b).
// bf16 MFMA both matmuls (fp32 accumulate); threshold 2e-2 >> bf16 err ~2e-3 (verified r1).

typedef __bf16 bf16x8 __attribute__((ext_vector_type(8)));
typedef float  f32x4  __attribute__((ext_vector_type(4)));

__device__ __forceinline__ void gl_lds16(const void* g, void* l) {
  __builtin_amdgcn_global_load_lds((const __attribute__((address_space(1))) void*)g,
                                   (__attribute__((address_space(3))) void*)l, 16, 0, 0);
}

__device__ __forceinline__ bf16x8 pack8(f32x4 a, f32x4 b) {
  bf16x8 r;
  r[0] = (__bf16)a[0]; r[1] = (__bf16)a[1]; r[2] = (__bf16)a[2]; r[3] = (__bf16)a[3];
  r[4] = (__bf16)b[0]; r[5] = (__bf16)b[1]; r[6] = (__bf16)b[2]; r[7] = (__bf16)b[3];
  return r;
}

// ---------------- Kernel 1: p = x@W^T + b ; pn = p/||p|| -> bf16 ----------------
// (unchanged — passed r1/r2)
__global__ __launch_bounds__(512, 1) void proj_kernel(
    const float* __restrict__ x, const float* __restrict__ W,
    const float* __restrict__ bq, __bf16* __restrict__ pn) {
  __shared__ __attribute__((aligned(16))) char ldsW[131072];
  const int t = threadIdx.x;
  const int lane = t & 63;
  const int w = t >> 6;

  #pragma unroll
  for (int it = 0; it < 16; ++it) {
    int base = (it * 512 + t) * 8;
    int row  = base >> 8;
    int colb = (base & 255) * 2;
    f32x4 v0 = *(const f32x4*)(W + base);
    f32x4 v1 = *(const f32x4*)(W + base + 4);
    *(bf16x8*)(ldsW + row * 512 + (colb ^ ((row & 7) << 4))) = pack8(v0, v1);
  }
  __syncthreads();

  const int r0 = blockIdx.x * 128 + w * 16;
  const int arow = r0 + (lane & 15);
  const float* xrow = x + (size_t)arow * 256 + (lane >> 4) * 8;
  bf16x8 afr[8];
  #pragma unroll
  for (int kk = 0; kk < 8; ++kk) {
    f32x4 v0 = *(const f32x4*)(xrow + kk * 32);
    f32x4 v1 = *(const f32x4*)(xrow + kk * 32 + 4);
    afr[kk] = pack8(v0, v1);
  }

  f32x4 acc[16];
  #pragma unroll
  for (int ct = 0; ct < 16; ++ct) acc[ct] = (f32x4){0.f, 0.f, 0.f, 0.f};
  const int kb0 = (lane >> 4) * 16;
  #pragma unroll
  for (int ct = 0; ct < 16; ++ct) {
    int brow = ct * 16 + (lane & 15);
    const char* wb = ldsW + brow * 512;
    int sw = (brow & 7) << 4;
    #pragma unroll
    for (int kk = 0; kk < 8; ++kk) {
      bf16x8 bf = *(const bf16x8*)(wb + ((kk * 64 + kb0) ^ sw));
      acc[ct] = __builtin_amdgcn_mfma_f32_16x16x32_bf16(afr[kk], bf, acc[ct], 0, 0, 0);
    }
  }

  float bc[16];
  #pragma unroll
  for (int ct = 0; ct < 16; ++ct) bc[ct] = bq[ct * 16 + (lane & 15)];
  #pragma unroll
  for (int ct = 0; ct < 16; ++ct) {
    #pragma unroll
    for (int r = 0; r < 4; ++r) acc[ct][r] += bc[ct];
  }
  #pragma unroll
  for (int r = 0; r < 4; ++r) {
    float s = 0.f;
    #pragma unroll
    for (int ct = 0; ct < 16; ++ct) s += acc[ct][r] * acc[ct][r];
    s += __shfl_xor(s, 1); s += __shfl_xor(s, 2);
    s += __shfl_xor(s, 4); s += __shfl_xor(s, 8);
    float rn = rsqrtf(s);
    int rowg = r0 + (lane >> 4) * 4 + r;
    __bf16* dst = pn + (size_t)rowg * 256 + (lane & 15);
    #pragma unroll
    for (int ct = 0; ct < 16; ++ct) dst[ct * 16] = (__bf16)(acc[ct][r] * rn);
  }
}

// ---------------- Kernel 2: attn[b] = pn[b] @ pn[b]^T ----------------
// v3: stripe pipeline + COUNTED vmcnt (T4). Per j-iter: raw s_barrier, issue next-B
// staging, compute, stores; end-of-iter s_waitcnt vmcnt(16) waits only for the staging
// loads (16 newest vmem = this iter's stores) so output stores stream across barriers.
// XCD-bijective swizzle: each XCD works 2 batches -> pn working set 2MB fits its L2.
__global__ __launch_bounds__(512, 4) void gram_kernel(
    const __bf16* __restrict__ pn, float* __restrict__ out) {
  __shared__ __attribute__((aligned(16))) char lds[65536];
  const int t = threadIdx.x;
  const int lane = t & 63;
  const int w = t >> 6;
  const int wr = w >> 1;        // 0..3: 32-row group
  const int wc = w & 1;         // 0..1: 32-col group
  // bijective chunked XCD swizzle (nwg=512, 512%8==0): XCD x gets vb in [x*64, x*64+64)
  const int vb = (blockIdx.x & 7) * 64 + (blockIdx.x >> 3);
  const int batch = vb >> 5;            // 32 blocks per batch
  const int stripe = (vb >> 1) & 15;    // 16 row-stripes of 128
  const int jhalf = vb & 1;             // 2 col-halves of 1024
  const char* pb = (const char*)(pn + (size_t)batch * 2048 * 256);
  const int i0 = stripe * 128;
  const int kb0 = (lane >> 4) * 16;

  // ---- stage A (128 rows x 512B = 64KB): linear LDS dest + pre-swizzled source ----
  #pragma unroll
  for (int i = 0; i < 8; ++i) {
    int off = (i * 512 + t) * 16;
    int row = off >> 9;
    int kb  = off & 511;
    gl_lds16(pb + (size_t)(i0 + row) * 512 + (kb ^ ((row & 7) << 4)),
             lds + i * 8192 + w * 1024);
  }
  __syncthreads();  // startup: full drain is fine here

  // ---- hoist A fragments: rows wr*32 + fr*16 + (lane&15), all K=256 ----
  bf16x8 afr[2][8];
  #pragma unroll
  for (int fr = 0; fr < 2; ++fr) {
    int row = wr * 32 + fr * 16 + (lane & 15);
    const char* ab = lds + row * 512;
    int sw = (row & 7) << 4;
    #pragma unroll
    for (int kk = 0; kk < 8; ++kk)
      afr[fr][kk] = *(const bf16x8*)(ab + ((kk * 64 + kb0) ^ sw));
  }
  __syncthreads();  // all A-frag reads done before B0 staging overwrites LDS

  const int jbase = jhalf * 1024;
  float* ob = out + (size_t)batch * 2048 * 2048;
  const int ro0 = i0 + wr * 32 + (lane >> 4) * 4;
  // per-thread B-row bases (row index within 64-row B tile)
  const int brow0 = wc * 32 + (lane & 15);
  const int brow1 = brow0 + 16;
  const int bsw0 = (brow0 & 7) << 4;
  const int bsw1 = (brow1 & 7) << 4;

  // ---- prologue: stage B(0) into buf0, drain (no stores in flight yet) ----
  #pragma unroll
  for (int i = 0; i < 4; ++i) {
    int off = (i * 512 + t) * 16;
    int row = off >> 9;
    int kb  = off & 511;
    gl_lds16(pb + (size_t)(jbase + row) * 512 + (kb ^ ((row & 7) << 4)),
             lds + i * 8192 + w * 1024);
  }
  asm volatile("s_waitcnt vmcnt(0)" ::: "memory");

  for (int jj = 0; jj < 16; ++jj) {
    __builtin_amdgcn_s_barrier();   // B(jj) staged & visible (vmcnt waited last iter)
    // issue staging of B(jj+1) into the other buffer; completes under compute
    if (jj < 15) {
      char* nb = lds + ((jj + 1) & 1) * 32768;
      int j0 = jbase + (jj + 1) * 64;
      #pragma unroll
      for (int i = 0; i < 4; ++i) {
        int off = (i * 512 + t) * 16;
        int row = off >> 9;
        int kb  = off & 511;
        gl_lds16(pb + (size_t)(j0 + row) * 512 + (kb ^ ((row & 7) << 4)),
                 nb + i * 8192 + w * 1024);
      }
    }
    asm volatile("" ::: "memory");  // pin: staging loads issue BEFORE stores below

    // compute 128x64 tile: wave (wr,wc) -> 32x32 = 2x2 MFMA frags x 8 k-steps
    const char* buf = lds + (jj & 1) * 32768;
    f32x4 acc[2][2];
    #pragma unroll
    for (int m = 0; m < 2; ++m)
      #pragma unroll
      for (int n = 0; n < 2; ++n) acc[m][n] = (f32x4){0.f, 0.f, 0.f, 0.f};
    #pragma unroll
    for (int kk = 0; kk < 8; ++kk) {
      int kb = kk * 64 + kb0;
      bf16x8 bfr[2];
      bfr[0] = *(const bf16x8*)(buf + brow0 * 512 + (kb ^ bsw0));
      bfr[1] = *(const bf16x8*)(buf + brow1 * 512 + (kb ^ bsw1));
      #pragma unroll
      for (int m = 0; m < 2; ++m)
        #pragma unroll
        for (int n = 0; n < 2; ++n)
          acc[m][n] = __builtin_amdgcn_mfma_f32_16x16x32_bf16(afr[m][kk], bfr[n], acc[m][n], 0, 0, 0);
    }

    // store tile jj (plain stores: L2 write-combines full lines); 16 dwords/thread
    int co0 = jbase + jj * 64 + wc * 32 + (lane & 15);
    #pragma unroll
    for (int m = 0; m < 2; ++m)
      #pragma unroll
      for (int n = 0; n < 2; ++n)
        #pragma unroll
        for (int r = 0; r < 4; ++r)
          ob[(size_t)(ro0 + m * 16 + r) * 2048 + (co0 + n * 16)] = acc[m][n][r];

    // counted wait: 16 newest vmem ops are THIS iter's stores -> staging loads of
    // B(jj+1) complete; stores stay in flight across the next barrier (T4).
    if (jj < 15)
      asm volatile("s_waitcnt vmcnt(16)" ::: "memory");
  }
}

extern "C" void kernel_launch(void* const* d_in, const int* in_sizes, int n_in,
                              void* d_out, int out_size, void* d_ws, size_t ws_size,
                              hipStream_t stream) {
  const float* x  = (const float*)d_in[0];   // [16,2048,256]
  const float* Wq = (const float*)d_in[1];   // [256,256]
  const float* bq = (const float*)d_in[2];   // [256]
  float* out = (float*)d_out;                // [16,2048,2048]
  __bf16* pn = (__bf16*)d_ws;                // 32768*256 bf16 = 16 MB scratch

  proj_kernel<<<dim3(256), dim3(512), 0, stream>>>(x, Wq, bq, pn);
  gram_kernel<<<dim3(512), dim3(512), 0, stream>>>(pn, out);
}